// Round 4
// baseline (253.811 us; speedup 1.0000x reference)
//
#include <hip/hip_runtime.h>

// PieceMaxPool: out[b, p*C + c] = max_l ( x[b,c,l] + (mask[b,l]==p+1 ? 0 : -100) )
// x: (B=256, C=768, L=256) fp32, mask: (B, L) int32 in [0,3], out: (B, 3*C) fp32.
// x is L3-resident (201 MiB < 256 MiB IF-cache, warmed by harness d_in restore):
// measured 13.4 TB/s in R3 (~15 us kernel). This round: cut VALU/elem ~30% via
// float4 elementwise accumulators (v_pk_add_f32-friendly) + per-row collapse,
// to test issue-bound vs L3-BW-bound.

constexpr int BB = 256;
constexpr int CC = 768;
constexpr int LL = 256;
constexpr int PP = 3;
constexpr float MINUS = -100.0f;

typedef float f32x4 __attribute__((ext_vector_type(4)));

constexpr int QUADS_PER_WAVE  = 3;                       // 12 rows per wave
constexpr int WAVES_PER_BLOCK = 4;
constexpr int ROWS_PER_BLOCK  = 4 * QUADS_PER_WAVE * WAVES_PER_BLOCK;  // 48
constexpr int BLOCKS_PER_B    = CC / ROWS_PER_BLOCK;     // 16

__device__ __forceinline__ f32x4 vmax4(f32x4 a, f32x4 b) {
    f32x4 r;
    r.x = fmaxf(a.x, b.x);
    r.y = fmaxf(a.y, b.y);
    r.z = fmaxf(a.z, b.z);
    r.w = fmaxf(a.w, b.w);
    return r;
}

__global__ __launch_bounds__(256) void piece_max_pool_kernel(
    const float* __restrict__ x,
    const int*   __restrict__ mask,
    float*       __restrict__ out)
{
    const int tid  = threadIdx.x;
    const int lane = tid & 63;
    const int g    = lane & 15;        // position within 16-lane row group
    const int rsub = lane >> 4;        // which of the 4 rows in the quad
    const int wave = tid >> 6;
    const int blk  = blockIdx.x;
    const int b    = blk / BLOCKS_PER_B;
    const int cbase = (blk % BLOCKS_PER_B) * ROWS_PER_BLOCK + wave * (4 * QUADS_PER_WAVE);

    // ---- per-lane bias vectors for its 16 l-positions: l = j*64 + g*4 + k ----
    // bias4[p][j] is a float4 of {0,-100}; reused for all 12 rows of this wave.
    f32x4 bias4[PP][4];
#pragma unroll
    for (int j = 0; j < 4; ++j) {
        const int4 m4 = *reinterpret_cast<const int4*>(mask + b * LL + j * 64 + g * 4);
        const int mm[4] = {m4.x, m4.y, m4.z, m4.w};
#pragma unroll
        for (int p = 0; p < PP; ++p) {
            f32x4 bv;
            bv.x = (mm[0] == p + 1) ? 0.0f : MINUS;
            bv.y = (mm[1] == p + 1) ? 0.0f : MINUS;
            bv.z = (mm[2] == p + 1) ? 0.0f : MINUS;
            bv.w = (mm[3] == p + 1) ? 0.0f : MINUS;
            bias4[p][j] = bv;
        }
    }

#pragma unroll
    for (int q = 0; q < QUADS_PER_WAVE; ++q) {
        const int c = cbase + q * 4 + rsub;               // this lane-group's row
        const float* rp = x + ((size_t)b * CC + c) * LL + g * 4;

        // Hoist all 4 loads (MLP), then compute.
        f32x4 v[4];
#pragma unroll
        for (int j = 0; j < 4; ++j)
            v[j] = __builtin_nontemporal_load(reinterpret_cast<const f32x4*>(rp + j * 64));

        // Elementwise float4 accumulators: per j per p = 2 v_pk_add_f32 + 4 v_max.
        f32x4 acc[PP];
#pragma unroll
        for (int p = 0; p < PP; ++p)
            acc[p] = v[0] + bias4[p][0];
#pragma unroll
        for (int j = 1; j < 4; ++j)
#pragma unroll
            for (int p = 0; p < PP; ++p)
                acc[p] = vmax4(acc[p], v[j] + bias4[p][j]);

        // Collapse 4 -> 1 per piece (3 max), then 4-step 16-lane butterfly.
        float mx[PP];
#pragma unroll
        for (int p = 0; p < PP; ++p)
            mx[p] = fmaxf(fmaxf(acc[p].x, acc[p].y), fmaxf(acc[p].z, acc[p].w));

#pragma unroll
        for (int off = 8; off >= 1; off >>= 1)
#pragma unroll
            for (int p = 0; p < PP; ++p)
                mx[p] = fmaxf(mx[p], __shfl_xor(mx[p], off, 16));

        if (g == 0) {
            float* o = out + (size_t)b * (PP * CC) + c;
#pragma unroll
            for (int p = 0; p < PP; ++p)
                o[(size_t)p * CC] = mx[p];
        }
    }
}

extern "C" void kernel_launch(void* const* d_in, const int* in_sizes, int n_in,
                              void* d_out, int out_size, void* d_ws, size_t ws_size,
                              hipStream_t stream)
{
    const float* x    = (const float*)d_in[0];
    const int*   mask = (const int*)d_in[1];
    float*       out  = (float*)d_out;

    const int grid = BB * BLOCKS_PER_B;  // 4096 blocks
    piece_max_pool_kernel<<<grid, WAVES_PER_BLOCK * 64, 0, stream>>>(x, mask, out);
}